// Round 5
// baseline (233.174 us; speedup 1.0000x reference)
//
#include <hip/hip_runtime.h>

typedef __bf16 bf16x8 __attribute__((ext_vector_type(8)));
typedef float  f32x4  __attribute__((ext_vector_type(4)));

#define TSEQ 2048
#define CDIM 1024
#define NHEAD 16
#define DH 64

__device__ __forceinline__ void gl_lds16(const void* g, void* l) {
  __builtin_amdgcn_global_load_lds(
      (const __attribute__((address_space(1))) unsigned int*)g,
      (__attribute__((address_space(3))) unsigned int*)l, 16, 0, 0);
}

template <int PAT>
__device__ __forceinline__ float swz(float x) {
  return __int_as_float(__builtin_amdgcn_ds_swizzle(__float_as_int(x), PAT));
}

__device__ __forceinline__ float fexp2(float x) { return __builtin_amdgcn_exp2f(x); }

// ---------------- fp32 -> bf16 conversion (vectorized) ----------------
__global__ __launch_bounds__(256) void cvt_bf16(const float* __restrict__ in,
                                                __bf16* __restrict__ out, int n8) {
  int i = blockIdx.x * 256 + threadIdx.x;
  if (i >= n8) return;
  const float4* p = (const float4*)(in + (size_t)i * 8);
  float4 a = p[0], b = p[1];
  bf16x8 r;
  r[0] = (__bf16)a.x; r[1] = (__bf16)a.y; r[2] = (__bf16)a.z; r[3] = (__bf16)a.w;
  r[4] = (__bf16)b.x; r[5] = (__bf16)b.y; r[6] = (__bf16)b.z; r[7] = (__bf16)b.w;
  *(bf16x8*)(out + (size_t)i * 8) = r;
}

// ---------------- bf16 GEMM (m97-style): out[M,N] = A[M,K]*Bw[N,K]^T + bias --------
template <int EPI>
__global__ __launch_bounds__(256) void gemm_bt(
    const __bf16* __restrict__ A, const __bf16* __restrict__ Bw,
    const float* __restrict__ bias, float* __restrict__ outf,
    __bf16* __restrict__ q_buf, __bf16* __restrict__ k_buf,
    __bf16* __restrict__ vT_buf, int M, int N, int K) {
  __shared__ alignas(16) __bf16 lda[128 * 64];
  __shared__ alignas(16) __bf16 ldb[128 * 64];
  const int tid = threadIdx.x;
  const int lane = tid & 63, wid = tid >> 6;
  const int wm = wid >> 1, wn = wid & 1;
  const int row0 = blockIdx.y * 128, col0 = blockIdx.x * 128;
  f32x4 acc[4][4] = {};

  const int srow = lane >> 3;
  const int scb = (lane & 7) * 16;

  for (int k0 = 0; k0 < K; k0 += 64) {
#pragma unroll
    for (int j = 0; j < 4; ++j) {
      int blk = j * 4 + wid;
      int r = blk * 8 + srow;
      char* la = (char*)lda + blk * 1024;
      char* lb = (char*)ldb + blk * 1024;
      gl_lds16((const char*)(A + (size_t)(row0 + r) * K + k0) + scb, la);
      gl_lds16((const char*)(Bw + (size_t)(col0 + r) * K + k0) + scb, lb);
    }
    __syncthreads();
#pragma unroll
    for (int kk = 0; kk < 2; ++kk) {
      bf16x8 af[4], bfr[4];
#pragma unroll
      for (int m = 0; m < 4; ++m)
        af[m] = *(const bf16x8*)&lda[(wm * 64 + m * 16 + (lane & 15)) * 64 + kk * 32 + (lane >> 4) * 8];
#pragma unroll
      for (int n = 0; n < 4; ++n)
        bfr[n] = *(const bf16x8*)&ldb[(wn * 64 + n * 16 + (lane & 15)) * 64 + kk * 32 + (lane >> 4) * 8];
#pragma unroll
      for (int m = 0; m < 4; ++m)
#pragma unroll
        for (int n = 0; n < 4; ++n)
          acc[m][n] = __builtin_amdgcn_mfma_f32_16x16x32_bf16(af[m], bfr[n], acc[m][n], 0, 0, 0);
    }
    __syncthreads();
  }
#pragma unroll
  for (int m = 0; m < 4; ++m) {
#pragma unroll
    for (int n = 0; n < 4; ++n) {
#pragma unroll
      for (int i = 0; i < 4; ++i) {
        int r = row0 + wm * 64 + m * 16 + (lane >> 4) * 4 + i;
        int c = col0 + wn * 64 + n * 16 + (lane & 15);
        float v = acc[m][n][i] + bias[c];
        if (EPI == 0) {
          outf[(size_t)r * N + c] = v;
        } else {
          int bb = r >> 11, t = r & 2047;
          int sec = c >> 10, cc = c & 1023;
          int hh = cc >> 6, d = cc & 63;
          size_t bh = (size_t)bb * NHEAD + hh;
          __bf16 bv = (__bf16)v;
          if (sec == 0)      q_buf[(bh * TSEQ + (size_t)t) * DH + d] = bv;
          else if (sec == 1) k_buf[(bh * TSEQ + (size_t)t) * DH + d] = bv;
          else               vT_buf[(bh * DH + (size_t)d) * TSEQ + t] = bv;
        }
      }
    }
  }
}

// ---------------- flash attention: 1 wave = one 16-row q-group ----------------
// grid (x=bh 32, y=qg 128): linear id consecutive in bh -> XCD r serves bh%8==r
// (4 heads, 2MB K/V, L2-fit). Heavy-first: qg = 127 - blockIdx.y.
// Occupancy-driven design: 4096 waves, VGPR<=128 -> 16 waves/CU.
__global__ __launch_bounds__(64, 4) void attn_fwd(
    const __bf16* __restrict__ q_buf, const __bf16* __restrict__ k_buf,
    const __bf16* __restrict__ vT_buf, __bf16* __restrict__ y_buf) {
  const int T = TSEQ;
  const int lane = threadIdx.x;
  const int bh = blockIdx.x;
  const int qg = 127 - (int)blockIdx.y;  // heavy groups dispatched first
  const int b = bh >> 4, h = bh & 15;
  const int row0 = qg * 16;
  const float scale2 = 0.125f * 1.44269504f;
  const float slope2 = exp2f(-0.5f * (float)(h + 1)) * 1.44269504f;
  const __bf16* qp = q_buf + (size_t)bh * T * DH;
  const __bf16* kp = k_buf + (size_t)bh * T * DH;
  const __bf16* vp = vT_buf + (size_t)bh * DH * T;

  // row stride 68 elems (34 dw): P-write banks (136g+34i+n*8+c/2)%32 disjoint per g
  __shared__ alignas(16) __bf16 p_lds[16][68];

  bf16x8 qf[2];
  {
    const __bf16* qr = &qp[(size_t)(row0 + (lane & 15)) * DH + (lane >> 4) * 8];
    qf[0] = *(const bf16x8*)qr;
    qf[1] = *(const bf16x8*)(qr + 32);
  }

  f32x4 o[4] = {};
  float mrow[4], lrow[4];
#pragma unroll
  for (int i = 0; i < 4; ++i) { mrow[i] = -__builtin_inff(); lrow[i] = 0.f; }

  const int klo = (lane & 15) * DH + (lane >> 4) * 8;
  const int vlo = (lane & 15) * T + (lane >> 4) * 8;
  const int kend = row0 + 15;
  const int qr0 = row0 + (lane >> 4) * 4;

  for (int kt = 0; kt <= kend; kt += 64) {
    // K tile + V tile loads issued up front; latency hides across waves (16/CU)
    bf16x8 kf[4][2], vf[4][2];
#pragma unroll
    for (int n = 0; n < 4; ++n) {
      const __bf16* kr = kp + (size_t)(kt + n * 16) * DH + klo;
      kf[n][0] = *(const bf16x8*)kr;
      kf[n][1] = *(const bf16x8*)(kr + 32);
      const __bf16* vr = vp + vlo + n * 16 * T + kt;
      vf[n][0] = *(const bf16x8*)vr;
      vf[n][1] = *(const bf16x8*)(vr + 32);
    }
    // S = Q K^T
    f32x4 s[4];
#pragma unroll
    for (int n = 0; n < 4; ++n) {
      f32x4 z = {};
      z = __builtin_amdgcn_mfma_f32_16x16x32_bf16(qf[0], kf[n][0], z, 0, 0, 0);
      s[n] = __builtin_amdgcn_mfma_f32_16x16x32_bf16(qf[1], kf[n][1], z, 0, 0, 0);
    }
    // scale + ALiBi + causal; row max
    float sv[4][4];
    float tmax[4] = {-__builtin_inff(), -__builtin_inff(), -__builtin_inff(), -__builtin_inff()};
#pragma unroll
    for (int n = 0; n < 4; ++n) {
      int kc = kt + n * 16 + (lane & 15);
#pragma unroll
      for (int i = 0; i < 4; ++i) {
        int r = qr0 + i;
        float x = (kc <= r) ? (s[n][i] * scale2 + slope2 * (float)(kc - r)) : -__builtin_inff();
        sv[n][i] = x;
        tmax[i] = fmaxf(tmax[i], x);
      }
    }
    // online softmax; 4 independent 16-lane trees
#pragma unroll
    for (int i = 0; i < 4; ++i) {
      float t = tmax[i];
      t = fmaxf(t, swz<0x041F>(t));
      t = fmaxf(t, swz<0x081F>(t));
      t = fmaxf(t, swz<0x101F>(t));
      t = fmaxf(t, swz<0x201F>(t));
      float mnew = fmaxf(mrow[i], t);
      float corr = fexp2(mrow[i] - mnew);
      mrow[i] = mnew;
      float rs = 0.f;
      float pf[4];
#pragma unroll
      for (int n = 0; n < 4; ++n) {
        pf[n] = fexp2(sv[n][i] - mnew);
        rs += pf[n];
      }
      rs += swz<0x041F>(rs);
      rs += swz<0x081F>(rs);
      rs += swz<0x101F>(rs);
      rs += swz<0x201F>(rs);
      lrow[i] = lrow[i] * corr + rs;
#pragma unroll
      for (int n2 = 0; n2 < 4; ++n2) o[n2][i] *= corr;
#pragma unroll
      for (int n = 0; n < 4; ++n)
        p_lds[(lane >> 4) * 4 + i][n * 16 + (lane & 15)] = (__bf16)pf[n];
    }
    // P D-layout -> A-frag (same-wave LDS roundtrip, no barrier)
    bf16x8 pa[2];
#pragma unroll
    for (int kk = 0; kk < 2; ++kk)
      pa[kk] = *(const bf16x8*)&p_lds[lane & 15][kk * 32 + (lane >> 4) * 8];
#pragma unroll
    for (int n2 = 0; n2 < 4; ++n2) {
      o[n2] = __builtin_amdgcn_mfma_f32_16x16x32_bf16(pa[0], vf[n2][0], o[n2], 0, 0, 0);
      o[n2] = __builtin_amdgcn_mfma_f32_16x16x32_bf16(pa[1], vf[n2][1], o[n2], 0, 0, 0);
    }
  }
  // normalize + write y in [B][T][C]
#pragma unroll
  for (int i = 0; i < 4; ++i) {
    float inv = 1.0f / lrow[i];
    int t = qr0 + i;
#pragma unroll
    for (int n2 = 0; n2 < 4; ++n2) {
      int d = n2 * 16 + (lane & 15);
      y_buf[((size_t)b * T + t) * CDIM + h * DH + d] = (__bf16)(o[n2][i] * inv);
    }
  }
}

extern "C" void kernel_launch(void* const* d_in, const int* in_sizes, int n_in,
                              void* d_out, int out_size, void* d_ws, size_t ws_size,
                              hipStream_t stream) {
  const float* x      = (const float*)d_in[0];
  const float* W_attn = (const float*)d_in[1];
  const float* b_attn = (const float*)d_in[2];
  const float* W_proj = (const float*)d_in[3];
  const float* b_proj = (const float*)d_in[4];
  float* out = (float*)d_out;
  char* ws = (char*)d_ws;
  const size_t MB = (size_t)1 << 20;
  __bf16* xb  = (__bf16*)(ws + 0 * MB);
  __bf16* wab = (__bf16*)(ws + 8 * MB);
  __bf16* wpb = (__bf16*)(ws + 14 * MB);
  __bf16* qbf = (__bf16*)(ws + 16 * MB);
  __bf16* kbf = (__bf16*)(ws + 24 * MB);
  __bf16* vtb = (__bf16*)(ws + 32 * MB);
  __bf16* yb  = (__bf16*)(ws + 40 * MB);

  cvt_bf16<<<2048, 256, 0, stream>>>(x, xb, 524288);
  cvt_bf16<<<1536, 256, 0, stream>>>(W_attn, wab, 393216);
  cvt_bf16<<<512, 256, 0, stream>>>(W_proj, wpb, 131072);

  gemm_bt<1><<<dim3(24, 32), 256, 0, stream>>>(xb, wab, b_attn, nullptr,
                                               qbf, kbf, vtb, 4096, 3072, 1024);
  attn_fwd<<<dim3(32, 128), 64, 0, stream>>>(qbf, kbf, vtb, yb);
  gemm_bt<0><<<dim3(8, 32), 256, 0, stream>>>(yb, wpb, b_proj, out,
                                              nullptr, nullptr, nullptr, 4096, 1024, 1024);
}